// Round 1
// 811.908 us; speedup vs baseline: 1.1057x; 1.1057x over previous
//
#include <hip/hip_runtime.h>
#include <hip/hip_bf16.h>
#include <cstdint>
#include <cstddef>

typedef __attribute__((ext_vector_type(8))) short short8;
typedef __attribute__((ext_vector_type(4))) float float4v;

#define L_SEQ 2048
#define N_B   4
#define E_DIM 2048
#define N_H   16
#define H_D   128
// (1/sqrt(128)) * log2(e)
#define C1_SCALE_LOG2E 0.12751744f

static __device__ __forceinline__ unsigned short f2bf(float f) {
  union { float f; unsigned int u; } x; x.f = f;
  unsigned int u = x.u;
  u = u + 0x7fffu + ((u >> 16) & 1u);   // round-to-nearest-even
  return (unsigned short)(u >> 16);
}

static __device__ __forceinline__ void g2l16(const void* g, void* l) {
  __builtin_amdgcn_global_load_lds(
      (const __attribute__((address_space(1))) unsigned int*)g,
      (__attribute__((address_space(3))) unsigned int*)l, 16, 0, 0);
}

// ---------------- fp32 -> bf16 conversion (8 elems/thread) ----------------
__global__ __launch_bounds__(256) void cvt_kernel(const float* __restrict__ in,
                                                  unsigned short* __restrict__ out,
                                                  int n8) {
  int i = blockIdx.x * blockDim.x + threadIdx.x;
  if (i >= n8) return;
  const float4* p = (const float4*)in;
  float4 a = p[2 * i];
  float4 b = p[2 * i + 1];
  short8 o;
  o[0] = (short)f2bf(a.x); o[1] = (short)f2bf(a.y);
  o[2] = (short)f2bf(a.z); o[3] = (short)f2bf(a.w);
  o[4] = (short)f2bf(b.x); o[5] = (short)f2bf(b.y);
  o[6] = (short)f2bf(b.z); o[7] = (short)f2bf(b.w);
  *(short8*)(out + 8 * (size_t)i) = o;
}

// ---------------- GEMM: C[m,n] = sum_k A[m,k]*B[n,k] + bias[n] --------------
// 256x256 tile, BK=64, 8 waves (2M x 4N), 512 threads, 128 KiB LDS.
// 8-phase counted-vmcnt schedule (guide T2+T3+T4+T5, m201 lineage):
//   LDS = 8 K-sliced buffers [256 rows][32 k] bf16 (16 KB each):
//     slot = buf*4 + mat*2 + ks   (buf = kt&1, mat 0=A 1=B, ks = K-half).
//   Per K-tile, 4 phases: {ks0/m-half0, ks0/m-half1, ks1/m-half0, ks1/m-half1}.
//   Slice death order per tile: B0 (after ph0), A0 (ph1), B1 (ph2), A1 (ph3);
//   each phase issues the replacement of the slice that died last phase ->
//   steady state 3 slices (6 loads/wave) in flight, vmcnt(6) at tile
//   boundaries, vmcnt(0) only once before the last tile.  Never drains
//   mid-loop (the m97 structure's ~20% stall).
// LDS swizzle: 16B chunk c of row r stored at c^(r&3) (pre-swizzled global
//   source, linear global_load_lds dest). Lane->bank check: ds_read_b128
//   frags land exactly 8 lanes per 16B bank-quad -> conflict-free.
// XCD remap: xcd = lin%8 owns an 8(n) x 4(m) patch of the 8x32 grid so its
//   L2 working set is the K-window of 12 panels, not 33.
// MODE 0: fp32 row-major out. MODE 1: bf16 (n,h,l,d). MODE 2: bf16 (n,h,d,l).
#define BAR2()                                         \
  do {                                                 \
    __builtin_amdgcn_s_barrier();                      \
    asm volatile("" ::: "memory");                     \
    __builtin_amdgcn_sched_barrier(0);                 \
  } while (0)

#define LGKM0() asm volatile("s_waitcnt lgkmcnt(0)" ::: "memory")

#define STAGE(MAT, KT, KS, SLOT)                                          \
  do {                                                                    \
    g2l16((MAT) + (size_t)soff[0] + (size_t)((KT) * 128 + (KS) * 64),     \
          (char*)lds + (SLOT) * 16384 + lbase[0]);                        \
    g2l16((MAT) + (size_t)soff[1] + (size_t)((KT) * 128 + (KS) * 64),     \
          (char*)lds + (SLOT) * 16384 + lbase[1]);                        \
  } while (0)

template <int MODE>
__global__ __launch_bounds__(512) void gemm256(const unsigned short* __restrict__ A,
                                               const unsigned short* __restrict__ B,
                                               const float* __restrict__ bias,
                                               void* __restrict__ Cout) {
  __shared__ unsigned short lds[8][8192];  // 128 KiB
  const int tid = threadIdx.x;
  const int wid = tid >> 6, ln = tid & 63;
  const int wm = wid >> 2, wn = wid & 3;
  const int lhi = ln >> 4, llo = ln & 15;

  const int lin = (int)blockIdx.x;
  const int xcd = lin & 7, sl = lin >> 3;
  const int n0 = (sl & 7) * 256;
  const int m0 = (xcd * 4 + (sl >> 3)) * 256;

  const char* Apan = (const char*)(A + (size_t)m0 * E_DIM);
  const char* Bpan = (const char*)(B + (size_t)n0 * E_DIM);

  // staging invariants: thread covers 16B chunks g = i*512 + wid*64 + ln
  // of a slice; row = g>>2, chunk c = g&3; source chunk pre-swizzled c^(r&3).
  int soff[2], lbase[2];
#pragma unroll
  for (int i = 0; i < 2; ++i) {
    const int g = i * 512 + wid * 64 + ln;
    const int row = g >> 2, c = g & 3;
    soff[i] = row * (E_DIM * 2) + ((c ^ (row & 3)) << 4);
    lbase[i] = (i * 512 + wid * 64) * 16;
  }

  float4v acc[8][4] = {};
  const int arow = wm * 128 + llo;            // A rows within 256-row tile
  const int brow = wn * 64 + llo;             // B rows (= C cols)
  const int swz = (lhi ^ (llo & 3)) * 8;      // swizzled 16B chunk, in shorts
  constexpr int NT = E_DIM / 64;              // 32 K-tiles

  // ---- prologue: kt0 all 4 slices; kt1's B0,A0,B1 (A1 comes at kt0 ph0) ----
  STAGE(Apan, 0, 0, 0); STAGE(Apan, 0, 1, 1);
  STAGE(Bpan, 0, 0, 2); STAGE(Bpan, 0, 1, 3);
  STAGE(Bpan, 1, 0, 6); STAGE(Apan, 1, 0, 4); STAGE(Bpan, 1, 1, 7);
  asm volatile("s_waitcnt vmcnt(6)" ::: "memory");  // kt0 landed; 3 in flight
  BAR2();

  short8 av[4], bv[4];
  for (int kt = 0; kt < NT; ++kt) {
    const int bb = kt & 1, ob = bb ^ 1;
    const unsigned short* pA = lds[bb * 4 + 0];  // +8192 shorts = ks1 slice
    const unsigned short* pB = lds[bb * 4 + 2];

    // ---- phase 0: ks0, m-rows 0..63 (8 ds_read_b128) ----
#pragma unroll
    for (int mr = 0; mr < 4; ++mr)
      av[mr] = *(const short8*)(pA + (arow + mr * 16) * 32 + swz);
#pragma unroll
    for (int nr = 0; nr < 4; ++nr)
      bv[nr] = *(const short8*)(pB + (brow + nr * 16) * 32 + swz);
    if (kt + 1 < NT) STAGE(Apan, kt + 1, 1, ob * 4 + 1);
    __builtin_amdgcn_s_barrier();
    LGKM0();
    __builtin_amdgcn_s_setprio(1);
#pragma unroll
    for (int mr = 0; mr < 4; ++mr)
#pragma unroll
      for (int nr = 0; nr < 4; ++nr)
        acc[mr][nr] = __builtin_amdgcn_mfma_f32_16x16x32_bf16(av[mr], bv[nr], acc[mr][nr], 0, 0, 0);
    __builtin_amdgcn_s_setprio(0);
    BAR2();  // B-ks0 slice now dead workgroup-wide

    // ---- phase 1: ks0, m-rows 64..127 (B frags reused in regs) ----
#pragma unroll
    for (int mr = 0; mr < 4; ++mr)
      av[mr] = *(const short8*)(pA + (arow + 64 + mr * 16) * 32 + swz);
    if (kt + 2 < NT) STAGE(Bpan, kt + 2, 0, bb * 4 + 2);
    __builtin_amdgcn_s_barrier();
    LGKM0();
    __builtin_amdgcn_s_setprio(1);
#pragma unroll
    for (int mr = 0; mr < 4; ++mr)
#pragma unroll
      for (int nr = 0; nr < 4; ++nr)
        acc[4 + mr][nr] = __builtin_amdgcn_mfma_f32_16x16x32_bf16(av[mr], bv[nr], acc[4 + mr][nr], 0, 0, 0);
    __builtin_amdgcn_s_setprio(0);
    BAR2();  // A-ks0 dead

    // ---- phase 2: ks1, m-rows 0..63 ----
#pragma unroll
    for (int mr = 0; mr < 4; ++mr)
      av[mr] = *(const short8*)(pA + 8192 + (arow + mr * 16) * 32 + swz);
#pragma unroll
    for (int nr = 0; nr < 4; ++nr)
      bv[nr] = *(const short8*)(pB + 8192 + (brow + nr * 16) * 32 + swz);
    if (kt + 2 < NT) STAGE(Apan, kt + 2, 0, bb * 4 + 0);
    __builtin_amdgcn_s_barrier();
    LGKM0();
    __builtin_amdgcn_s_setprio(1);
#pragma unroll
    for (int mr = 0; mr < 4; ++mr)
#pragma unroll
      for (int nr = 0; nr < 4; ++nr)
        acc[mr][nr] = __builtin_amdgcn_mfma_f32_16x16x32_bf16(av[mr], bv[nr], acc[mr][nr], 0, 0, 0);
    __builtin_amdgcn_s_setprio(0);
    BAR2();  // B-ks1 dead

    // ---- phase 3: ks1, m-rows 64..127 ----
#pragma unroll
    for (int mr = 0; mr < 4; ++mr)
      av[mr] = *(const short8*)(pA + 8192 + (arow + 64 + mr * 16) * 32 + swz);
    if (kt + 2 < NT) STAGE(Bpan, kt + 2, 1, bb * 4 + 3);
    __builtin_amdgcn_s_barrier();
    LGKM0();
    __builtin_amdgcn_s_setprio(1);
#pragma unroll
    for (int mr = 0; mr < 4; ++mr)
#pragma unroll
      for (int nr = 0; nr < 4; ++nr)
        acc[4 + mr][nr] = __builtin_amdgcn_mfma_f32_16x16x32_bf16(av[mr], bv[nr], acc[4 + mr][nr], 0, 0, 0);
    __builtin_amdgcn_s_setprio(0);

    // ---- tile boundary: next tile's 4 slices landed; 3 newer in flight ----
    if (kt < NT - 1) {
      if (kt == NT - 2) { asm volatile("s_waitcnt vmcnt(0)" ::: "memory"); }
      else              { asm volatile("s_waitcnt vmcnt(6)" ::: "memory"); }
      BAR2();
    }
  }

  // ---- epilogue ----
  float bcol[4];
#pragma unroll
  for (int nr = 0; nr < 4; ++nr) bcol[nr] = bias[n0 + wn * 64 + nr * 16 + llo];

#pragma unroll
  for (int mr = 0; mr < 8; ++mr) {
#pragma unroll
    for (int r = 0; r < 4; ++r) {
      const int m = m0 + wm * 128 + mr * 16 + lhi * 4 + r;
      const int l = m >> 2, nb = m & 3;
#pragma unroll
      for (int nr = 0; nr < 4; ++nr) {
        const int cN = n0 + wn * 64 + nr * 16 + llo;
        const float v = acc[mr][nr][r] + bcol[nr];
        if (MODE == 0) {
          ((float*)Cout)[(size_t)m * E_DIM + cN] = v;
        } else if (MODE == 1) {
          const int h = cN >> 7, d = cN & 127;
          ((unsigned short*)Cout)[(((size_t)(nb * N_H + h)) * L_SEQ + l) * H_D + d] = f2bf(v);
        } else {
          const int h = cN >> 7, d = cN & 127;
          ((unsigned short*)Cout)[(((size_t)(nb * N_H + h)) * H_D + d) * L_SEQ + l] = f2bf(v);
        }
      }
    }
  }
}

// ---------------- flash attention (causal), BM=BN=128, 512 threads ---------
// Q,K: (n,h,l,d) bf16.  VT: (n,h,d,l) bf16.  Cc out: (l*N_B+n, h*128+d) bf16.
// 8 waves; wave wv owns Q-rows [wv*16, wv*16+16).  (Unchanged this round.)
__global__ __launch_bounds__(512, 2) void flash_attn(const unsigned short* __restrict__ Q,
                                                     const unsigned short* __restrict__ K,
                                                     const unsigned short* __restrict__ VT,
                                                     unsigned short* __restrict__ Cc) {
  __shared__ unsigned short sK[128 * 128];  // K tile -> P tile -> O tile
  __shared__ unsigned short sV[128 * 128];  // V^T tile (d, key)
  const int tid = threadIdx.x;
  const int wv = tid >> 6, ln = tid & 63;
  const int lhi = ln >> 4, llo = ln & 15;
  const int kr = lhi * 8;
  const int lin = (int)blockIdx.x;
  const int xcd = lin & 7, slot = lin >> 3;
  const int hgrp = slot >> 4, pos = slot & 15;
  const int tq = (hgrp & 1) ? (15 - pos) : pos;  // zigzag: balances CU load
  const int nh = hgrp * 8 + xcd;
  const size_t hoff = (size_t)nh * (L_SEQ * H_D);
  const unsigned short* Qp = Q + hoff;
  const char* Kb = (const char*)(K + hoff);
  const char* Vb = (const char*)(VT + hoff);

  short8 qf[4];
#pragma unroll
  for (int kk = 0; kk < 4; ++kk)
    qf[kk] = *(const short8*)(Qp + (size_t)(tq * 128 + wv * 16 + llo) * H_D + kk * 32 + kr);

  float4v o_acc[8] = {};
  float mst[4], lst[4];
#pragma unroll
  for (int r = 0; r < 4; ++r) { mst[r] = -1e30f; lst[r] = 0.f; }

  for (int j = 0; j <= tq; ++j) {
#pragma unroll
    for (int t = 0; t < 4; ++t) {
      const int row = wv * 16 + t * 4 + lhi;
      const int sc = llo ^ (row & 7);
      g2l16(Kb + ((size_t)(j * 128 + row) * H_D) * 2 + sc * 16,
            (char*)sK + wv * 4096 + t * 1024);
      g2l16(Vb + ((size_t)row * L_SEQ + j * 128) * 2 + sc * 16,
            (char*)sV + wv * 4096 + t * 1024);
    }
    __syncthreads();

    float4v s[8] = {};
#pragma unroll
    for (int kk = 0; kk < 4; ++kk) {
      const int u0 = kk * 4 + lhi;
#pragma unroll
      for (int jj = 0; jj < 8; ++jj) {
        const int row = jj * 16 + llo;
        const short8 b = *(const short8*)(sK + row * 128 + (u0 ^ (row & 7)) * 8);
        s[jj] = __builtin_amdgcn_mfma_f32_16x16x32_bf16(qf[kk], b, s[jj], 0, 0, 0);
      }
    }

#pragma unroll
    for (int jj = 0; jj < 8; ++jj)
#pragma unroll
      for (int r = 0; r < 4; ++r)
        s[jj][r] *= C1_SCALE_LOG2E;
    const bool diag = (j == tq);
    if (diag) {
      const int qrow = wv * 16 + lhi * 4;
#pragma unroll
      for (int jj = 0; jj < 8; ++jj) {
        const int c = jj * 16 + llo;
#pragma unroll
        for (int r = 0; r < 4; ++r)
          if (c > qrow + r) s[jj][r] = -1e30f;
      }
    }

    float alpha[4];
#pragma unroll
    for (int r = 0; r < 4; ++r) {
      float rm = fmaxf(fmaxf(fmaxf(s[0][r], s[1][r]), fmaxf(s[2][r], s[3][r])),
                       fmaxf(fmaxf(s[4][r], s[5][r]), fmaxf(s[6][r], s[7][r])));
      rm = fmaxf(rm, __shfl_xor(rm, 1, 64));
      rm = fmaxf(rm, __shfl_xor(rm, 2, 64));
      rm = fmaxf(rm, __shfl_xor(rm, 4, 64));
      rm = fmaxf(rm, __shfl_xor(rm, 8, 64));
      const float mnew = fmaxf(mst[r], rm);
      const float a = __builtin_exp2f(mst[r] - mnew);
      mst[r] = mnew;
      alpha[r] = a;
      float rs = 0.f;
#pragma unroll
      for (int jj = 0; jj < 8; ++jj) {
        const float pv = __builtin_exp2f(s[jj][r] - mnew);
        s[jj][r] = pv;
        rs += pv;
      }
      rs += __shfl_xor(rs, 1, 64);
      rs += __shfl_xor(rs, 2, 64);
      rs += __shfl_xor(rs, 4, 64);
      rs += __shfl_xor(rs, 8, 64);
      lst[r] = lst[r] * a + rs;
    }

    __syncthreads();

#pragma unroll
    for (int r = 0; r < 4; ++r) {
      const int rl = wv * 16 + lhi * 4 + r;
#pragma unroll
      for (int jj = 0; jj < 8; ++jj) {
        const int c = jj * 16 + llo;
        const float v = s[jj][r];
        const float v2 = __shfl_xor(v, 1, 64);
        if ((llo & 1) == 0) {
          const unsigned int pk = (unsigned int)f2bf(v) | ((unsigned int)f2bf(v2) << 16);
          const int u = ((c >> 3) ^ (rl & 7));
          *(unsigned int*)(sK + rl * 128 + u * 8 + (c & 7)) = pk;
        }
      }
    }

#pragma unroll
    for (int jj = 0; jj < 8; ++jj) {
      float4v t = o_acc[jj];
      t[0] *= alpha[0]; t[1] *= alpha[1];
      t[2] *= alpha[2]; t[3] *= alpha[3];
      o_acc[jj] = t;
    }
#pragma unroll
    for (int kk = 0; kk < 4; ++kk) {
      const int u0 = kk * 4 + lhi;
      const int rowp = wv * 16 + llo;
      const short8 a = *(const short8*)(sK + rowp * 128 + (u0 ^ (rowp & 7)) * 8);
#pragma unroll
      for (int jj = 0; jj < 8; ++jj) {
        const int row = jj * 16 + llo;
        const short8 b = *(const short8*)(sV + row * 128 + (u0 ^ (row & 7)) * 8);
        o_acc[jj] = __builtin_amdgcn_mfma_f32_16x16x32_bf16(a, b, o_acc[jj], 0, 0, 0);
      }
    }
    __syncthreads();
  }

  const int nb = nh >> 4, h = nh & 15;
#pragma unroll
  for (int r = 0; r < 4; ++r) {
    const float inv = 1.0f / lst[r];
    const int rl = wv * 16 + lhi * 4 + r;
#pragma unroll
    for (int jj = 0; jj < 8; ++jj) {
      const int c = jj * 16 + llo;
      const float v = o_acc[jj][r] * inv;
      const float v2 = __shfl_xor(v, 1, 64);
      if ((llo & 1) == 0) {
        const unsigned int pk = (unsigned int)f2bf(v) | ((unsigned int)f2bf(v2) << 16);
        *(unsigned int*)(sK + rl * 128 + c) = pk;
      }
    }
  }
  __syncthreads();
#pragma unroll
  for (int t = 0; t < 4; ++t) {
    const int row = wv * 16 + t * 4 + lhi;
    const short8 val = *(const short8*)(sK + row * 128 + llo * 8);
    const int qg = tq * 128 + row;
    *(short8*)(Cc + ((size_t)qg * N_B + nb) * E_DIM + h * H_D + llo * 8) = val;
  }
}

// ---------------------------------------------------------------------------
extern "C" void kernel_launch(void* const* d_in, const int* in_sizes, int n_in,
                              void* d_out, int out_size, void* d_ws, size_t ws_size,
                              hipStream_t stream) {
  (void)in_sizes; (void)n_in; (void)out_size; (void)ws_size;
  const float* query = (const float*)d_in[0];
  const float* key   = (const float*)d_in[1];
  const float* wq = (const float*)d_in[2];
  const float* bq = (const float*)d_in[3];
  const float* wk = (const float*)d_in[4];
  const float* bk = (const float*)d_in[5];
  const float* wv = (const float*)d_in[6];
  const float* bv = (const float*)d_in[7];
  const float* wo = (const float*)d_in[8];
  const float* bo = (const float*)d_in[9];

  char* ws = (char*)d_ws;
  unsigned short* Xq = (unsigned short*)(ws);               // 32 MiB
  unsigned short* Xk = (unsigned short*)(ws + 33554432);    // 32 MiB
  unsigned short* Wq = (unsigned short*)(ws + 67108864);    // 8 MiB
  unsigned short* Wk = (unsigned short*)(ws + 75497472);
  unsigned short* Wv = (unsigned short*)(ws + 83886080);
  unsigned short* Wo = (unsigned short*)(ws + 92274688);
  unsigned short* Qh = (unsigned short*)(ws + 100663296);   // 32 MiB (n,h,l,d)
  unsigned short* Kh = (unsigned short*)(ws + 134217728);   // 32 MiB (n,h,l,d)
  unsigned short* VT = (unsigned short*)(ws + 167772160);   // 32 MiB (n,h,d,l)
  unsigned short* Cc = Xq;  // context aliases Xq (Xq dead after Q-projection)

  const int nAct8 = L_SEQ * N_B * E_DIM / 8;  // 2,097,152
  const int nW8   = E_DIM * E_DIM / 8;        //   524,288
  cvt_kernel<<<dim3((nAct8 + 255) / 256), 256, 0, stream>>>(query, Xq, nAct8);
  cvt_kernel<<<dim3((nAct8 + 255) / 256), 256, 0, stream>>>(key, Xk, nAct8);
  cvt_kernel<<<dim3((nW8 + 255) / 256), 256, 0, stream>>>(wq, Wq, nW8);
  cvt_kernel<<<dim3((nW8 + 255) / 256), 256, 0, stream>>>(wk, Wk, nW8);
  cvt_kernel<<<dim3((nW8 + 255) / 256), 256, 0, stream>>>(wv, Wv, nW8);
  cvt_kernel<<<dim3((nW8 + 255) / 256), 256, 0, stream>>>(wo, Wo, nW8);

  // 256x256-tile GEMMs: grid = (2048/256)*(8192/256) = 256 blocks, 512 thr
  dim3 gg(256);
  gemm256<1><<<gg, 512, 0, stream>>>(Xq, Wq, bq, Qh);
  gemm256<1><<<gg, 512, 0, stream>>>(Xk, Wk, bk, Kh);
  gemm256<2><<<gg, 512, 0, stream>>>(Xk, Wv, bv, VT);

  flash_attn<<<dim3(N_B * N_H * (L_SEQ / 128)), 512, 0, stream>>>(Qh, Kh, VT, Cc);

  gemm256<0><<<gg, 512, 0, stream>>>(Cc, Wo, bo, d_out);
}